// Round 7
// baseline (264.448 us; speedup 1.0000x reference)
//
#include <hip/hip_runtime.h>
#include <hip/hip_bf16.h>
#include <math.h>

#define MM 256
#define LL 4096
#define TT 2048

typedef __attribute__((ext_vector_type(8))) short bf16x8;
typedef __attribute__((ext_vector_type(4))) float f32x4;
typedef __attribute__((ext_vector_type(4))) unsigned short us4;
typedef unsigned short ushort_t;

// workspace float offsets
#define OFF_Q      262144
#define OFF_D      266240
#define OFF_V      270336
#define OFF_U      274432
#define OFF_UP     278528
#define OFF_RINVP  290816
#define OFF_GP     421888
#define OFF_APL    552960
#define OFF_XPL    2650112
#define OFF_ATP    3698688
#define OFF_WTP    5795840
// gram partials alias the WTP window (disjoint in time)
#define OFF_PA     5795840
#define OFF_PX     8417280
// Newton split-bf16 plane buffers
#define OFF_E0P    9990144
#define OFF_EAP    10252288
#define OFF_EBP    10514432
#define OFF_XAT    10776576
#define OFF_XBT    10907648

#define MFMA3(ACC, AH, AL, BH, BL)                                              \
  ACC = __builtin_amdgcn_mfma_f32_16x16x32_bf16(AH, BH, ACC, 0, 0, 0);          \
  ACC = __builtin_amdgcn_mfma_f32_16x16x32_bf16(AH, BL, ACC, 0, 0, 0);          \
  ACC = __builtin_amdgcn_mfma_f32_16x16x32_bf16(AL, BH, ACC, 0, 0, 0);

__device__ __forceinline__ void split_bf16(float x, ushort_t& h, ushort_t& l) {
  __hip_bfloat16 bh = __float2bfloat16(x);
  h = *(ushort_t*)&bh;
  __hip_bfloat16 bl = __float2bfloat16(x - __bfloat162float(bh));
  l = *(ushort_t*)&bl;
}
__device__ __forceinline__ float bfu2f(ushort_t u) {
  unsigned v = ((unsigned)u) << 16;
  float f;
  __builtin_memcpy(&f, &v, 4);
  return f;
}

__device__ __forceinline__ float wave_red_sum(float v) {
#pragma unroll
  for (int o = 32; o > 0; o >>= 1) v += __shfl_down(v, o);
  return v;
}
__device__ __forceinline__ float wave_red_max(float v) {
#pragma unroll
  for (int o = 32; o > 0; o >>= 1) v = fmaxf(v, __shfl_down(v, o));
  return v;
}
__device__ float blk_red_sum(float v) {
  __shared__ float sh[4];
  int lane = threadIdx.x & 63, wv = threadIdx.x >> 6;
  v = wave_red_sum(v);
  __syncthreads();
  if (lane == 0) sh[wv] = v;
  __syncthreads();
  return sh[0] + sh[1] + sh[2] + sh[3];
}
__device__ float blk_red_max(float v) {
  __shared__ float shm[4];
  int lane = threadIdx.x & 63, wv = threadIdx.x >> 6;
  v = wave_red_max(v);
  __syncthreads();
  if (lane == 0) shm[wv] = v;
  __syncthreads();
  return fmaxf(fmaxf(shm[0], shm[1]), fmaxf(shm[2], shm[3]));
}

// ---------------- prep (proven round-4 structure) ----------------
__global__ __launch_bounds__(256) void k_prep(float* __restrict__ ws,
                                              const float* __restrict__ Are,
                                              const float* __restrict__ Aim,
                                              const float* __restrict__ Xre,
                                              const float* __restrict__ Xim,
                                              const float* __restrict__ gamma) {
  __shared__ float tr[32][33], ti[32][33];
  int bid = blockIdx.x, tid = threadIdx.x;
  if (bid < 8) {
    ((float4*)(ws + OFF_Q))[bid * 256 + tid] = make_float4(0.f, 0.f, 0.f, 0.f);
  } else if (bid < 1032) {
    int i4 = (bid - 8) * 256 + tid;
    ushort_t* dst = (ushort_t*)(ws + OFF_APL);
    float4 re = ((const float4*)Are)[i4];
    float4 im = ((const float4*)Aim)[i4];
    float4 ga = ((const float4*)gamma)[i4 & (LL / 4 - 1)];
    float sr[4] = {re.x * sqrtf(ga.x), re.y * sqrtf(ga.y), re.z * sqrtf(ga.z), re.w * sqrtf(ga.w)};
    float si[4] = {im.x * sqrtf(ga.x), im.y * sqrtf(ga.y), im.z * sqrtf(ga.z), im.w * sqrtf(ga.w)};
    us4 hr, lr, hi, li;
#pragma unroll
    for (int e = 0; e < 4; ++e) {
      ushort_t h, l;
      split_bf16(sr[e], h, l); hr[e] = h; lr[e] = l;
      split_bf16(si[e], h, l); hi[e] = h; li[e] = l;
    }
    size_t o = (size_t)i4 * 4;
    *(us4*)(dst + o) = hr;
    *(us4*)(dst + (size_t)MM * LL + o) = lr;
    *(us4*)(dst + 2 * (size_t)MM * LL + o) = hi;
    *(us4*)(dst + 3 * (size_t)MM * LL + o) = li;
  } else if (bid < 1544) {
    int i4 = (bid - 1032) * 256 + tid;
    ushort_t* dst = (ushort_t*)(ws + OFF_XPL);
    float4 re = ((const float4*)Xre)[i4];
    float4 im = ((const float4*)Xim)[i4];
    float fr[4] = {re.x, re.y, re.z, re.w};
    float fi[4] = {im.x, im.y, im.z, im.w};
    us4 hr, lr, hi, li;
#pragma unroll
    for (int e = 0; e < 4; ++e) {
      ushort_t h, l;
      split_bf16(fr[e], h, l); hr[e] = h; lr[e] = l;
      split_bf16(fi[e], h, l); hi[e] = h; li[e] = l;
    }
    size_t o = (size_t)i4 * 4;
    *(us4*)(dst + o) = hr;
    *(us4*)(dst + (size_t)MM * TT + o) = lr;
    *(us4*)(dst + 2 * (size_t)MM * TT + o) = hi;
    *(us4*)(dst + 3 * (size_t)MM * TT + o) = li;
  } else {
    int b2 = bid - 1544;
    ushort_t* dst = (ushort_t*)(ws + OFF_ATP);
    int c0 = (b2 & 127) * 32, r0 = (b2 >> 7) * 32;
    int tx = tid & 31, tg = tid >> 5;
#pragma unroll
    for (int i = 0; i < 4; ++i) {
      int r = tg + 8 * i;
      tr[r][tx] = Are[(size_t)(r0 + r) * LL + c0 + tx];
      ti[r][tx] = Aim[(size_t)(r0 + r) * LL + c0 + tx];
    }
    __syncthreads();
#pragma unroll
    for (int i = 0; i < 4; ++i) {
      int rr = tg + 8 * i;
      size_t o = (size_t)(c0 + rr) * 256 + r0 + tx;
      ushort_t h, l;
      split_bf16(tr[tx][rr], h, l);
      dst[o] = h;
      dst[o + 1048576] = l;
      split_bf16(ti[tx][rr], h, l);
      dst[o + 2097152] = h;
      dst[o + 3145728] = l;
    }
  }
}

// ---------------- gram (combined A+X, 480 blocks) ----------------
__global__ __launch_bounds__(256, 4) void k_gram_both(float* __restrict__ ws) {
  __shared__ __align__(16) ushort_t sA[4][64][40];
  __shared__ __align__(16) ushort_t sB[4][64][40];
  const int ti_lu[10] = {0, 1, 1, 2, 2, 2, 3, 3, 3, 3};
  const int tj_lu[10] = {0, 0, 1, 0, 1, 2, 0, 1, 2, 3};
  int bid = blockIdx.x;
  const ushort_t* pl;
  float2* P;
  int K, tile, ksplit;
  size_t PS;
  if (bid < 320) {
    pl = (const ushort_t*)(ws + OFF_APL);
    P = (float2*)(ws + OFF_PA) + (size_t)bid * 4096;
    K = LL;
    PS = (size_t)MM * LL;
    tile = bid % 10;
    ksplit = bid / 10;
  } else {
    int b2 = bid - 320;
    pl = (const ushort_t*)(ws + OFF_XPL);
    P = (float2*)(ws + OFF_PX) + (size_t)b2 * 4096;
    K = TT;
    PS = (size_t)MM * TT;
    tile = b2 % 10;
    ksplit = b2 / 10;
  }
  int kbeg = ksplit * 128;
  int i0 = ti_lu[tile] * 64, j0 = tj_lu[tile] * 64;
  bool diag = (i0 == j0);
  int tid = threadIdx.x;
  int lane = tid & 63, wv = tid >> 6;
  int srow = tid >> 2, sslot = tid & 3;
  int arow = wv * 16 + (lane & 15);
  int kq = (lane >> 4) * 8;
  f32x4 z = {0.f, 0.f, 0.f, 0.f};
  f32x4 Zrr[4], Zri[4], Zir[4], Zii[4];
#pragma unroll
  for (int s = 0; s < 4; ++s) { Zrr[s] = z; Zri[s] = z; Zir[s] = z; Zii[s] = z; }

  for (int chunk = 0; chunk < 4; ++chunk) {
    int k0 = kbeg + chunk * 32;
    __syncthreads();
#pragma unroll
    for (int p = 0; p < 4; ++p) {
      *(bf16x8*)&sA[p][srow][sslot * 8] =
          *(const bf16x8*)(pl + p * PS + (size_t)(i0 + srow) * K + k0 + sslot * 8);
      if (!diag)
        *(bf16x8*)&sB[p][srow][sslot * 8] =
            *(const bf16x8*)(pl + p * PS + (size_t)(j0 + srow) * K + k0 + sslot * 8);
    }
    __syncthreads();
    bf16x8 arh = *(const bf16x8*)&sA[0][arow][kq];
    bf16x8 arl = *(const bf16x8*)&sA[1][arow][kq];
    bf16x8 aih = *(const bf16x8*)&sA[2][arow][kq];
    bf16x8 ail = *(const bf16x8*)&sA[3][arow][kq];
    ushort_t(*bs)[64][40] = diag ? sA : sB;
#pragma unroll
    for (int s = 0; s < 4; ++s) {
      int brow = s * 16 + (lane & 15);
      bf16x8 brh = *(const bf16x8*)&bs[0][brow][kq];
      bf16x8 brl = *(const bf16x8*)&bs[1][brow][kq];
      bf16x8 bih = *(const bf16x8*)&bs[2][brow][kq];
      bf16x8 bil = *(const bf16x8*)&bs[3][brow][kq];
      MFMA3(Zrr[s], arh, arl, brh, brl);
      MFMA3(Zri[s], arh, arl, bih, bil);
      MFMA3(Zir[s], aih, ail, brh, brl);
      MFMA3(Zii[s], aih, ail, bih, bil);
    }
  }
  int lrb = wv * 16 + (lane >> 4) * 4;
#pragma unroll
  for (int s = 0; s < 4; ++s) {
    int lc = s * 16 + (lane & 15);
#pragma unroll
    for (int r = 0; r < 4; ++r) {
      float re = Zrr[s][r] + Zii[s][r];   // a * conj(b)
      float im = Zir[s][r] - Zri[s][r];
      P[(lrb + r) * 64 + lc] = make_float2(re, im);
    }
  }
}

// ---------------- red_n1: fused partial-reduce + E0/X1 plane emit + Gp ----------------
// blocks [0,256): row i = bid, thread j = tid. Re-derive R(i,j), Dii, Djj from PA
// partials with the SAME fp32 summation order as the old reduce (bitwise identical),
// then emit E0 (rm+tr) and X1 (tr) split-bf16 planes. R is never materialized.
// blocks [256,512): Gp conversion from PX partials (unchanged numerics).
__global__ __launch_bounds__(256) void k_red_n1(float* __restrict__ ws) {
  int bid = blockIdx.x, tid = threadIdx.x;
  if (bid < 256) {
    const float2* PA = (const float2*)(ws + OFF_PA);
    ushort_t* e0 = (ushort_t*)(ws + OFF_E0P);
    ushort_t* e0t = e0 + 262144;
    ushort_t* x1t = (ushort_t*)(ws + OFF_XAT);
    int i = bid, j = tid;
    int ti = i >> 6, tj = j >> 6;
    // Dii (diag tile sum + ridge), identical order to old reduce
    int td_i = ((ti * (ti + 1)) >> 1) + ti;
    int e_i = (i & 63) * 65;
    float Dii = 0.f;
#pragma unroll 4
    for (int k = 0; k < 32; ++k) Dii += PA[(size_t)(k * 10 + td_i) * 4096 + e_i].x;
    Dii += 0.01f;
    // Djj (diag tile sum + ridge)
    int td_j = ((tj * (tj + 1)) >> 1) + tj;
    int e_j = (j & 63) * 65;
    float Djj = 0.f;
#pragma unroll 4
    for (int k = 0; k < 32; ++k) Djj += PA[(size_t)(k * 10 + td_j) * 4096 + e_j].x;
    Djj += 0.01f;
    // R(i,j), mirror-aware (upper tile = conj of lower)
    int ii = i, jj = j;
    float sgn = 1.f;
    if (ti < tj) { ii = j; jj = i; sgn = -1.f; }
    int tii = ii >> 6, tjj = jj >> 6;
    int t = ((tii * (tii + 1)) >> 1) + tjj;
    int e = ((ii & 63) << 6) + (jj & 63);
    float sx = 0.f, sy = 0.f;
#pragma unroll 4
    for (int k = 0; k < 32; ++k) {
      float2 p = PA[(size_t)(k * 10 + t) * 4096 + e];
      sx += p.x; sy += p.y;
    }
    if (i == j) sx += 0.01f;   // ridge (before use, same as old reduce-then-read)
    sy *= sgn;
    // n1 formulas (identical to old k_n1p)
    float dl = (i == j) ? 1.0f : 0.0f;
    float ex = dl - sx / Dii, ey = -sy / Dii;
    float xx = (dl + ex) / Djj, xy = ey / Djj;
    int rm = i * 256 + j, trn = j * 256 + i;
    ushort_t h, l;
    split_bf16(ex, h, l);
    e0[rm] = h; e0[rm + 65536] = l;
    e0t[trn] = h; e0t[trn + 65536] = l;
    split_bf16(ey, h, l);
    e0[rm + 131072] = h; e0[rm + 196608] = l;
    e0t[trn + 131072] = h; e0t[trn + 196608] = l;
    split_bf16(xx, h, l);
    x1t[trn] = h; x1t[trn + 65536] = l;
    split_bf16(xy, h, l);
    x1t[trn + 131072] = h; x1t[trn + 196608] = l;
  } else {
    const float2* PX = (const float2*)(ws + OFF_PX);
    ushort_t* dst = (ushort_t*)(ws + OFF_GP);
    int idx = (bid - 256) * 256 + tid;
    int i = idx >> 8, j = idx & 255;
    int ii = i, jj = j;
    float sgn = 1.f;
    if ((i >> 6) < (j >> 6)) { ii = j; jj = i; sgn = -1.f; }
    int ti = ii >> 6, tj = jj >> 6;
    int t = ((ti * (ti + 1)) >> 1) + tj;
    int e = ((ii & 63) << 6) + (jj & 63);
    float sx = 0.f, sy = 0.f;
#pragma unroll 4
    for (int k = 0; k < 16; ++k) {
      float2 p = PX[(size_t)(k * 10 + t) * 4096 + e];
      sx += p.x; sy += p.y;
    }
    sy *= sgn;
    ushort_t h, l;
    split_bf16(sx, h, l);
    dst[idx] = h;
    dst[idx + 65536] = l;
    split_bf16(sy, h, l);
    dst[idx + 131072] = h;
    dst[idx + 196608] = l;
  }
}

// ---------------- prim: 256^3 complex MFMA product, 64-row x 16-col tiles --------------
__global__ __launch_bounds__(256) void k_prim(const ushort_t* __restrict__ Arm,
                                              const ushort_t* __restrict__ BtrE,
                                              const ushort_t* __restrict__ BtrX,
                                              const ushort_t* __restrict__ AddX,
                                              ushort_t* __restrict__ EoutRm,
                                              ushort_t* __restrict__ EoutTr,
                                              ushort_t* __restrict__ XoutTr,
                                              ushort_t* __restrict__ XoutRm,
                                              int nEjobs) {
  __shared__ __align__(16) ushort_t sB[4][16][40];
  int job = blockIdx.x;
  bool isE = job < nEjobs;
  int b = isE ? job : job - nEjobs;
  const ushort_t* Bp = isE ? BtrE : BtrX;
  const ushort_t* Add = isE ? (const ushort_t*)nullptr : AddX;
  ushort_t* Otr = isE ? EoutTr : XoutTr;
  ushort_t* Orm = isE ? EoutRm : XoutRm;
  int j0 = (b & 15) * 16, i0 = (b >> 4) * 64;
  int tid = threadIdx.x;
  int lane = tid & 63, wv = tid >> 6;
  int sp = tid >> 6;
  int srow = (tid >> 2) & 15, sslot = tid & 3;
  int m = i0 + wv * 16 + (lane & 15);
  int kq = (lane >> 4) * 8;
  f32x4 Zrr = {0.f, 0.f, 0.f, 0.f}, Zri = Zrr, Zir = Zrr, Zii = Zrr;
  for (int k0 = 0; k0 < 256; k0 += 32) {
    __syncthreads();
    *(bf16x8*)&sB[sp][srow][sslot * 8] =
        *(const bf16x8*)(Bp + (size_t)sp * 65536 + (size_t)(j0 + srow) * 256 + k0 + sslot * 8);
    __syncthreads();
    size_t ao = (size_t)m * 256 + k0 + kq;
    bf16x8 arh = *(const bf16x8*)(Arm + ao);
    bf16x8 arl = *(const bf16x8*)(Arm + 65536 + ao);
    bf16x8 aih = *(const bf16x8*)(Arm + 131072 + ao);
    bf16x8 ail = *(const bf16x8*)(Arm + 196608 + ao);
    int brow = lane & 15;
    bf16x8 brh = *(const bf16x8*)&sB[0][brow][kq];
    bf16x8 brl = *(const bf16x8*)&sB[1][brow][kq];
    bf16x8 bih = *(const bf16x8*)&sB[2][brow][kq];
    bf16x8 bil = *(const bf16x8*)&sB[3][brow][kq];
    MFMA3(Zrr, arh, arl, brh, brl);
    MFMA3(Zri, arh, arl, bih, bil);
    MFMA3(Zir, aih, ail, brh, brl);
    MFMA3(Zii, aih, ail, bih, bil);
  }
  int rbase = i0 + wv * 16 + (lane >> 4) * 4;
  int col = j0 + (lane & 15);
  size_t wo = (size_t)col * 256 + rbase;
  us4 adr, adl, adi, adj;
  if (Add) {
    adr = *(const us4*)(Add + wo);
    adl = *(const us4*)(Add + 65536 + wo);
    adi = *(const us4*)(Add + 131072 + wo);
    adj = *(const us4*)(Add + 196608 + wo);
  }
  us4 hr, lr, hi, li;
#pragma unroll
  for (int r = 0; r < 4; ++r) {
    float re = Zrr[r] - Zii[r];   // complex a*b
    float im = Zri[r] + Zir[r];
    if (Add) {
      re += bfu2f(adr[r]) + bfu2f(adl[r]);
      im += bfu2f(adi[r]) + bfu2f(adj[r]);
    }
    ushort_t h, l;
    split_bf16(re, h, l); hr[r] = h; lr[r] = l;
    split_bf16(im, h, l); hi[r] = h; li[r] = l;
  }
  if (Otr) {
    *(us4*)(Otr + wo) = hr;
    *(us4*)(Otr + 65536 + wo) = lr;
    *(us4*)(Otr + 131072 + wo) = hi;
    *(us4*)(Otr + 196608 + wo) = li;
  }
  if (Orm) {
#pragma unroll
    for (int r = 0; r < 4; ++r) {
      size_t o = (size_t)(rbase + r) * 256 + col;
      Orm[o] = hr[r];
      Orm[o + 65536] = lr[r];
      Orm[o + 131072] = hi[r];
      Orm[o + 196608] = li[r];
    }
  }
}

// ---------------- wide MFMA ----------------
__global__ __launch_bounds__(256) void k_wide_mfma(const ushort_t* __restrict__ Ap,
                                                   const ushort_t* __restrict__ Bp,
                                                   const float* __restrict__ AuxRe,
                                                   const float* __restrict__ AuxIm,
                                                   ushort_t* __restrict__ WTout,
                                                   float* __restrict__ dq, int mode) {
  __shared__ __align__(16) ushort_t sB[4][32][40];
  const ushort_t* arh_p = Ap;
  const ushort_t* arl_p = Ap + 65536;
  const ushort_t* aih_p = Ap + 131072;
  const ushort_t* ail_p = Ap + 196608;
  const ushort_t* brh_p = Bp;
  const ushort_t* brl_p = Bp + 1048576;
  const ushort_t* bih_p = Bp + 2097152;
  const ushort_t* bil_p = Bp + 3145728;
  int job = blockIdx.x;
  int j0 = (job & 127) * 32;
  int i0 = (job >> 7) * 64;
  int tid = threadIdx.x;
  int lane = tid & 63, wv = tid >> 6;
  int spos = tid & 127;
  int srow = spos >> 2, sslot = spos & 3;
  int p0 = (tid >> 7) * 2;
  const ushort_t* bp0 = (p0 == 0) ? brh_p : bih_p;
  const ushort_t* bp1 = (p0 == 0) ? brl_p : bil_p;
  int m = i0 + wv * 16 + (lane & 15);
  int kq = (lane >> 4) * 8;
  f32x4 z = {0.f, 0.f, 0.f, 0.f};
  f32x4 Zrr[2], Zri[2], Zir[2], Zii[2];
#pragma unroll
  for (int s = 0; s < 2; ++s) { Zrr[s] = z; Zri[s] = z; Zir[s] = z; Zii[s] = z; }
  for (int k0 = 0; k0 < 256; k0 += 32) {
    __syncthreads();
    {
      size_t bo = (size_t)(j0 + srow) * 256 + k0 + sslot * 8;
      *(bf16x8*)&sB[p0][srow][sslot * 8] = *(const bf16x8*)(bp0 + bo);
      *(bf16x8*)&sB[p0 + 1][srow][sslot * 8] = *(const bf16x8*)(bp1 + bo);
    }
    __syncthreads();
    size_t ao = (size_t)m * 256 + k0 + kq;
    bf16x8 arh = *(const bf16x8*)(arh_p + ao);
    bf16x8 arl = *(const bf16x8*)(arl_p + ao);
    bf16x8 aih = *(const bf16x8*)(aih_p + ao);
    bf16x8 ail = *(const bf16x8*)(ail_p + ao);
#pragma unroll
    for (int s = 0; s < 2; ++s) {
      int brow = s * 16 + (lane & 15);
      bf16x8 brh = *(const bf16x8*)&sB[0][brow][kq];
      bf16x8 brl = *(const bf16x8*)&sB[1][brow][kq];
      bf16x8 bih = *(const bf16x8*)&sB[2][brow][kq];
      bf16x8 bil = *(const bf16x8*)&sB[3][brow][kq];
      MFMA3(Zrr[s], arh, arl, brh, brl);
      MFMA3(Zri[s], arh, arl, bih, bil);
      MFMA3(Zir[s], aih, ail, brh, brl);
      MFMA3(Zii[s], aih, ail, bih, bil);
    }
  }
  int rbase = i0 + wv * 16 + (lane >> 4) * 4;
#pragma unroll
  for (int s = 0; s < 2; ++s) {
    int col = j0 + s * 16 + (lane & 15);
    size_t wo = (size_t)col * 256 + rbase;
    float part = 0.f;
    if (mode == 0) {
      us4 hr, lr, hi, li;
#pragma unroll
      for (int r = 0; r < 4; ++r) {
        float re = Zrr[s][r] - Zii[s][r];
        float im = Zri[s][r] + Zir[s][r];
        ushort_t h, l;
        split_bf16(re, h, l);
        hr[r] = h; lr[r] = l;
        split_bf16(im, h, l);
        hi[r] = h; li[r] = l;
        size_t o = (size_t)(rbase + r) * LL + col;
        part += re * AuxRe[o] - im * AuxIm[o];
      }
      *(us4*)(WTout + wo) = hr;
      *(us4*)(WTout + 1048576 + wo) = lr;
      *(us4*)(WTout + 2097152 + wo) = hi;
      *(us4*)(WTout + 3145728 + wo) = li;
    } else {
      us4 wh = *(const us4*)(brh_p + wo);
      us4 wl = *(const us4*)(brl_p + wo);
      us4 wih = *(const us4*)(bih_p + wo);
      us4 wil = *(const us4*)(bil_p + wo);
#pragma unroll
      for (int r = 0; r < 4; ++r) {
        float re = Zrr[s][r] - Zii[s][r];
        float im = Zri[s][r] + Zir[s][r];
        float wx = bfu2f(wh[r]) + bfu2f(wl[r]);
        float wy = bfu2f(wih[r]) + bfu2f(wil[r]);
        part += wx * re + wy * im;
      }
    }
    part += __shfl_down(part, 32);
    part += __shfl_down(part, 16);
    if ((lane >> 4) == 0) atomicAdd(dq + col, part);
  }
}

// ---------------- v,u + LayerNorm (1024 threads, single pass) ----------------
__global__ __launch_bounds__(1024) void k_uvln(float* __restrict__ ws,
                                               const float* __restrict__ gamma,
                                               const float* __restrict__ delta,
                                               const float* __restrict__ lnw,
                                               const float* __restrict__ lnb) {
  __shared__ float sh[16];
  int tid = threadIdx.x, lane = tid & 63, wv = tid >> 6;
  float4 q4 = ((const float4*)(ws + OFF_Q))[tid];
  float4 d4 = ((const float4*)(ws + OFF_D))[tid];
  float4 g4 = ((const float4*)gamma)[tid];
  float dlt = 1.0f / (1.0f + expf(-delta[0]));
  float v0 = q4.x / (d4.x + 1e-12f), v1 = q4.y / (d4.y + 1e-12f);
  float v2 = q4.z / (d4.z + 1e-12f), v3 = q4.w / (d4.w + 1e-12f);
  float u0 = g4.x + dlt * (v0 - g4.x), u1 = g4.y + dlt * (v1 - g4.y);
  float u2 = g4.z + dlt * (v2 - g4.z), u3 = g4.w + dlt * (v3 - g4.w);
  ((float4*)(ws + OFF_V))[tid] = make_float4(v0, v1, v2, v3);
  ((float4*)(ws + OFF_U))[tid] = make_float4(u0, u1, u2, u3);
  float s = wave_red_sum(u0 + u1 + u2 + u3);
  if (lane == 0) sh[wv] = s;
  __syncthreads();
  float mu = 0.f;
#pragma unroll
  for (int w = 0; w < 16; ++w) mu += sh[w];
  mu *= (1.0f / LL);
  __syncthreads();
  float d0 = u0 - mu, d1 = u1 - mu, d2 = u2 - mu, d3 = u3 - mu;
  float s2 = wave_red_sum(d0 * d0 + d1 * d1 + d2 * d2 + d3 * d3);
  if (lane == 0) sh[wv] = s2;
  __syncthreads();
  float var = 0.f;
#pragma unroll
  for (int w = 0; w < 16; ++w) var += sh[w];
  var *= (1.0f / LL);
  float inv = rsqrtf(var + 1e-5f);
  float4 w4 = ((const float4*)lnw)[tid];
  float4 b4 = ((const float4*)lnb)[tid];
  ((float4*)(ws + OFF_UP))[tid] =
      make_float4(d0 * inv * w4.x + b4.x, d1 * inv * w4.y + b4.y,
                  d2 * inv * w4.z + b4.z, d3 * inv * w4.w + b4.w);
}

// ---------------- gate + attention + combine ----------------
__global__ __launch_bounds__(256) void k_gateattn(const float* __restrict__ ws,
                                                  const float* __restrict__ Wg,
                                                  const float* __restrict__ gb,
                                                  const float* __restrict__ inw,
                                                  const float* __restrict__ inb,
                                                  const float* __restrict__ outw,
                                                  const float* __restrict__ outb,
                                                  const float* __restrict__ gamma,
                                                  const float* __restrict__ lmbda,
                                                  float* __restrict__ out) {
  const float* uvec = ws + OFF_U;
  const float* up = ws + OFF_UP;
  const float* vvec = ws + OFF_V;
  int i = blockIdx.x, tid = threadIdx.x;
  const float4* wr = (const float4*)(Wg + (size_t)i * LL);
  const float4* u4 = (const float4*)uvec;
  float s = 0.f;
  for (int j = tid; j < LL / 4; j += 256) {
    float4 w = wr[j], x = u4[j];
    s += w.x * x.x + w.y * x.y + w.z * x.z + w.w * x.w;
  }
  float tot = blk_red_sum(s);
  float g = 1.0f / (1.0f + expf(-(tot + gb[i])));
  float qv = up[i] * inw[0] + inb[0];
  float w1 = inw[1], b1 = inb[1], w2 = inw[2], b2 = inb[2];
  const float4* up4 = (const float4*)up;
  float mx = -3.4e38f;
  for (int j = tid; j < LL / 4; j += 256) {
    float4 u = up4[j];
    mx = fmaxf(mx, fmaxf(fmaxf(qv * (u.x * w1 + b1), qv * (u.y * w1 + b1)),
                         fmaxf(qv * (u.z * w1 + b1), qv * (u.w * w1 + b1))));
  }
  mx = blk_red_max(mx);
  float den = 0.f, num = 0.f;
  for (int j = tid; j < LL / 4; j += 256) {
    float4 u = up4[j];
    float e0 = expf(qv * (u.x * w1 + b1) - mx);
    float e1 = expf(qv * (u.y * w1 + b1) - mx);
    float e2 = expf(qv * (u.z * w1 + b1) - mx);
    float e3 = expf(qv * (u.w * w1 + b1) - mx);
    den += e0 + e1 + e2 + e3;
    num += e0 * (u.x * w2 + b2) + e1 * (u.y * w2 + b2) + e2 * (u.z * w2 + b2) + e3 * (u.w * w2 + b2);
  }
  den = blk_red_sum(den);
  num = blk_red_sum(num);
  if (tid == 0) {
    float attn = (num / den) * outw[0] + outb[0];
    float r = g * vvec[i] + (1.0f - g) * gamma[i] + attn - lmbda[0];
    out[i] = fmaxf(r, 0.0f);
  }
}

extern "C" void kernel_launch(void* const* d_in, const int* in_sizes, int n_in,
                              void* d_out, int out_size, void* d_ws, size_t ws_size,
                              hipStream_t stream) {
  const float* gamma = (const float*)d_in[0];
  const float* Are   = (const float*)d_in[1];
  const float* Aim   = (const float*)d_in[2];
  const float* Xre   = (const float*)d_in[3];
  const float* Xim   = (const float*)d_in[4];
  const float* lnw   = (const float*)d_in[5];
  const float* lnb   = (const float*)d_in[6];
  const float* inw   = (const float*)d_in[7];
  const float* inb   = (const float*)d_in[8];
  const float* outw  = (const float*)d_in[9];
  const float* outb  = (const float*)d_in[10];
  const float* gateW = (const float*)d_in[11];
  const float* gateb = (const float*)d_in[12];
  const float* delta = (const float*)d_in[13];
  const float* lmbda = (const float*)d_in[14];
  float* out = (float*)d_out;
  float* ws = (float*)d_ws;

  ushort_t* e0rm = (ushort_t*)(ws + OFF_E0P);
  ushort_t* e0tr = e0rm + 262144;
  ushort_t* eArm = (ushort_t*)(ws + OFF_EAP);
  ushort_t* eAtr = eArm + 262144;
  ushort_t* eBrm = (ushort_t*)(ws + OFF_EBP);
  ushort_t* eBtr = eBrm + 262144;
  ushort_t* xAt = (ushort_t*)(ws + OFF_XAT);
  ushort_t* xBt = (ushort_t*)(ws + OFF_XBT);
  ushort_t* Rinvp = (ushort_t*)(ws + OFF_RINVP);

  k_prep<<<2568, 256, 0, stream>>>(ws, Are, Aim, Xre, Xim, gamma);
  k_gram_both<<<480, 256, 0, stream>>>(ws);
  k_red_n1<<<512, 256, 0, stream>>>(ws);                               // R-reduce + E0/X1 + Gp
  // Newton chain on split-bf16 planes (MFMA), 16-col tiles:
  k_prim<<<64, 256, 0, stream>>>(e0rm, e0tr, nullptr, nullptr,
                                 eArm, eAtr, nullptr, nullptr, 64);    // E1 = E0^2
  k_prim<<<128, 256, 0, stream>>>(eArm, eAtr, xAt, xAt,
                                  eBrm, eBtr, xBt, nullptr, 64);       // E2, X2
  k_prim<<<128, 256, 0, stream>>>(eBrm, eBtr, xBt, xBt,
                                  eArm, eAtr, xAt, nullptr, 64);       // E3, X3
  k_prim<<<128, 256, 0, stream>>>(eArm, eAtr, xAt, xAt,
                                  eBrm, eBtr, xBt, nullptr, 64);       // E4, X4
  k_prim<<<64, 256, 0, stream>>>(eBrm, nullptr, xBt, xBt,
                                 nullptr, nullptr, nullptr, Rinvp, 0); // X5 -> Rinvp
  k_wide_mfma<<<512, 256, 0, stream>>>(Rinvp, (const ushort_t*)(ws + OFF_ATP),
                                       Are, Aim, (ushort_t*)(ws + OFF_WTP),
                                       ws + OFF_D, 0);
  k_wide_mfma<<<512, 256, 0, stream>>>((const ushort_t*)(ws + OFF_GP),
                                       (const ushort_t*)(ws + OFF_WTP),
                                       nullptr, nullptr, nullptr, ws + OFF_Q, 1);
  k_uvln<<<1, 1024, 0, stream>>>(ws, gamma, delta, lnw, lnb);
  k_gateattn<<<LL, 256, 0, stream>>>(ws, gateW, gateb, inw, inb, outw, outb,
                                     gamma, lmbda, out);
}

// Round 8
// 250.650 us; speedup vs baseline: 1.0550x; 1.0550x over previous
//
#include <hip/hip_runtime.h>
#include <hip/hip_bf16.h>
#include <math.h>

#define MM 256
#define LL 4096
#define TT 2048

typedef __attribute__((ext_vector_type(8))) short bf16x8;
typedef __attribute__((ext_vector_type(4))) float f32x4;
typedef __attribute__((ext_vector_type(4))) unsigned short us4;
typedef unsigned short ushort_t;

// workspace float offsets
#define OFF_Q      262144
#define OFF_D      266240
#define OFF_V      270336
#define OFF_U      274432
#define OFF_UP     278528
#define OFF_RINVP  290816
#define OFF_GP     421888
#define OFF_APL    552960
#define OFF_XPL    2650112
#define OFF_ATP    3698688
#define OFF_WTP    5795840
// gram partials alias the WTP window (disjoint in time)
#define OFF_PA     5795840
#define OFF_PX     8417280
// Newton split-bf16 plane buffers
#define OFF_E0P    9990144
#define OFF_EAP    10252288
#define OFF_EBP    10514432
#define OFF_XAT    10776576
#define OFF_XBT    10907648

#define MFMA3(ACC, AH, AL, BH, BL)                                              \
  ACC = __builtin_amdgcn_mfma_f32_16x16x32_bf16(AH, BH, ACC, 0, 0, 0);          \
  ACC = __builtin_amdgcn_mfma_f32_16x16x32_bf16(AH, BL, ACC, 0, 0, 0);          \
  ACC = __builtin_amdgcn_mfma_f32_16x16x32_bf16(AL, BH, ACC, 0, 0, 0);

__device__ __forceinline__ void split_bf16(float x, ushort_t& h, ushort_t& l) {
  __hip_bfloat16 bh = __float2bfloat16(x);
  h = *(ushort_t*)&bh;
  __hip_bfloat16 bl = __float2bfloat16(x - __bfloat162float(bh));
  l = *(ushort_t*)&bl;
}
__device__ __forceinline__ float bfu2f(ushort_t u) {
  unsigned v = ((unsigned)u) << 16;
  float f;
  __builtin_memcpy(&f, &v, 4);
  return f;
}

__device__ __forceinline__ void tile_ij(int t, int& ti, int& tj) {
  float f = sqrtf(8.0f * (float)t + 1.0f);
  ti = (int)((f - 1.0f) * 0.5f + 0.001f);
  tj = t - ((ti * (ti + 1)) >> 1);
}

__device__ __forceinline__ float wave_red_sum(float v) {
#pragma unroll
  for (int o = 32; o > 0; o >>= 1) v += __shfl_down(v, o);
  return v;
}
__device__ __forceinline__ float wave_red_max(float v) {
#pragma unroll
  for (int o = 32; o > 0; o >>= 1) v = fmaxf(v, __shfl_down(v, o));
  return v;
}
__device__ float blk_red_sum(float v) {
  __shared__ float sh[4];
  int lane = threadIdx.x & 63, wv = threadIdx.x >> 6;
  v = wave_red_sum(v);
  __syncthreads();
  if (lane == 0) sh[wv] = v;
  __syncthreads();
  return sh[0] + sh[1] + sh[2] + sh[3];
}
__device__ float blk_red_max(float v) {
  __shared__ float shm[4];
  int lane = threadIdx.x & 63, wv = threadIdx.x >> 6;
  v = wave_red_max(v);
  __syncthreads();
  if (lane == 0) shm[wv] = v;
  __syncthreads();
  return fmaxf(fmaxf(shm[0], shm[1]), fmaxf(shm[2], shm[3]));
}

__device__ __forceinline__ float2 r_mirror(const float2* __restrict__ R, int i, int j) {
  if ((i >> 6) >= (j >> 6)) return R[i * 256 + j];
  float2 r = R[j * 256 + i];
  r.y = -r.y;
  return r;
}

// ---------------- prep (proven round-4 structure) ----------------
__global__ __launch_bounds__(256) void k_prep(float* __restrict__ ws,
                                              const float* __restrict__ Are,
                                              const float* __restrict__ Aim,
                                              const float* __restrict__ Xre,
                                              const float* __restrict__ Xim,
                                              const float* __restrict__ gamma) {
  __shared__ float tr[32][33], ti[32][33];
  int bid = blockIdx.x, tid = threadIdx.x;
  if (bid < 8) {
    ((float4*)(ws + OFF_Q))[bid * 256 + tid] = make_float4(0.f, 0.f, 0.f, 0.f);
  } else if (bid < 1032) {
    int i4 = (bid - 8) * 256 + tid;
    ushort_t* dst = (ushort_t*)(ws + OFF_APL);
    float4 re = ((const float4*)Are)[i4];
    float4 im = ((const float4*)Aim)[i4];
    float4 ga = ((const float4*)gamma)[i4 & (LL / 4 - 1)];
    float sr[4] = {re.x * sqrtf(ga.x), re.y * sqrtf(ga.y), re.z * sqrtf(ga.z), re.w * sqrtf(ga.w)};
    float si[4] = {im.x * sqrtf(ga.x), im.y * sqrtf(ga.y), im.z * sqrtf(ga.z), im.w * sqrtf(ga.w)};
    us4 hr, lr, hi, li;
#pragma unroll
    for (int e = 0; e < 4; ++e) {
      ushort_t h, l;
      split_bf16(sr[e], h, l); hr[e] = h; lr[e] = l;
      split_bf16(si[e], h, l); hi[e] = h; li[e] = l;
    }
    size_t o = (size_t)i4 * 4;
    *(us4*)(dst + o) = hr;
    *(us4*)(dst + (size_t)MM * LL + o) = lr;
    *(us4*)(dst + 2 * (size_t)MM * LL + o) = hi;
    *(us4*)(dst + 3 * (size_t)MM * LL + o) = li;
  } else if (bid < 1544) {
    int i4 = (bid - 1032) * 256 + tid;
    ushort_t* dst = (ushort_t*)(ws + OFF_XPL);
    float4 re = ((const float4*)Xre)[i4];
    float4 im = ((const float4*)Xim)[i4];
    float fr[4] = {re.x, re.y, re.z, re.w};
    float fi[4] = {im.x, im.y, im.z, im.w};
    us4 hr, lr, hi, li;
#pragma unroll
    for (int e = 0; e < 4; ++e) {
      ushort_t h, l;
      split_bf16(fr[e], h, l); hr[e] = h; lr[e] = l;
      split_bf16(fi[e], h, l); hi[e] = h; li[e] = l;
    }
    size_t o = (size_t)i4 * 4;
    *(us4*)(dst + o) = hr;
    *(us4*)(dst + (size_t)MM * TT + o) = lr;
    *(us4*)(dst + 2 * (size_t)MM * TT + o) = hi;
    *(us4*)(dst + 3 * (size_t)MM * TT + o) = li;
  } else {
    int b2 = bid - 1544;
    ushort_t* dst = (ushort_t*)(ws + OFF_ATP);
    int c0 = (b2 & 127) * 32, r0 = (b2 >> 7) * 32;
    int tx = tid & 31, tg = tid >> 5;
#pragma unroll
    for (int i = 0; i < 4; ++i) {
      int r = tg + 8 * i;
      tr[r][tx] = Are[(size_t)(r0 + r) * LL + c0 + tx];
      ti[r][tx] = Aim[(size_t)(r0 + r) * LL + c0 + tx];
    }
    __syncthreads();
#pragma unroll
    for (int i = 0; i < 4; ++i) {
      int rr = tg + 8 * i;
      size_t o = (size_t)(c0 + rr) * 256 + r0 + tx;
      ushort_t h, l;
      split_bf16(tr[tx][rr], h, l);
      dst[o] = h;
      dst[o + 1048576] = l;
      split_bf16(ti[tx][rr], h, l);
      dst[o + 2097152] = h;
      dst[o + 3145728] = l;
    }
  }
}

// ---------------- gram (combined A+X, 480 blocks) ----------------
__global__ __launch_bounds__(256, 4) void k_gram_both(float* __restrict__ ws) {
  __shared__ __align__(16) ushort_t sA[4][64][40];
  __shared__ __align__(16) ushort_t sB[4][64][40];
  const int ti_lu[10] = {0, 1, 1, 2, 2, 2, 3, 3, 3, 3};
  const int tj_lu[10] = {0, 0, 1, 0, 1, 2, 0, 1, 2, 3};
  int bid = blockIdx.x;
  const ushort_t* pl;
  float2* P;
  int K, tile, ksplit;
  size_t PS;
  if (bid < 320) {
    pl = (const ushort_t*)(ws + OFF_APL);
    P = (float2*)(ws + OFF_PA) + (size_t)bid * 4096;
    K = LL;
    PS = (size_t)MM * LL;
    tile = bid % 10;
    ksplit = bid / 10;
  } else {
    int b2 = bid - 320;
    pl = (const ushort_t*)(ws + OFF_XPL);
    P = (float2*)(ws + OFF_PX) + (size_t)b2 * 4096;
    K = TT;
    PS = (size_t)MM * TT;
    tile = b2 % 10;
    ksplit = b2 / 10;
  }
  int kbeg = ksplit * 128;
  int i0 = ti_lu[tile] * 64, j0 = tj_lu[tile] * 64;
  bool diag = (i0 == j0);
  int tid = threadIdx.x;
  int lane = tid & 63, wv = tid >> 6;
  int srow = tid >> 2, sslot = tid & 3;
  int arow = wv * 16 + (lane & 15);
  int kq = (lane >> 4) * 8;
  f32x4 z = {0.f, 0.f, 0.f, 0.f};
  f32x4 Zrr[4], Zri[4], Zir[4], Zii[4];
#pragma unroll
  for (int s = 0; s < 4; ++s) { Zrr[s] = z; Zri[s] = z; Zir[s] = z; Zii[s] = z; }

  for (int chunk = 0; chunk < 4; ++chunk) {
    int k0 = kbeg + chunk * 32;
    __syncthreads();
#pragma unroll
    for (int p = 0; p < 4; ++p) {
      *(bf16x8*)&sA[p][srow][sslot * 8] =
          *(const bf16x8*)(pl + p * PS + (size_t)(i0 + srow) * K + k0 + sslot * 8);
      if (!diag)
        *(bf16x8*)&sB[p][srow][sslot * 8] =
            *(const bf16x8*)(pl + p * PS + (size_t)(j0 + srow) * K + k0 + sslot * 8);
    }
    __syncthreads();
    bf16x8 arh = *(const bf16x8*)&sA[0][arow][kq];
    bf16x8 arl = *(const bf16x8*)&sA[1][arow][kq];
    bf16x8 aih = *(const bf16x8*)&sA[2][arow][kq];
    bf16x8 ail = *(const bf16x8*)&sA[3][arow][kq];
    ushort_t(*bs)[64][40] = diag ? sA : sB;
#pragma unroll
    for (int s = 0; s < 4; ++s) {
      int brow = s * 16 + (lane & 15);
      bf16x8 brh = *(const bf16x8*)&bs[0][brow][kq];
      bf16x8 brl = *(const bf16x8*)&bs[1][brow][kq];
      bf16x8 bih = *(const bf16x8*)&bs[2][brow][kq];
      bf16x8 bil = *(const bf16x8*)&bs[3][brow][kq];
      MFMA3(Zrr[s], arh, arl, brh, brl);
      MFMA3(Zri[s], arh, arl, bih, bil);
      MFMA3(Zir[s], aih, ail, brh, brl);
      MFMA3(Zii[s], aih, ail, bih, bil);
    }
  }
  int lrb = wv * 16 + (lane >> 4) * 4;
#pragma unroll
  for (int s = 0; s < 4; ++s) {
    int lc = s * 16 + (lane & 15);
#pragma unroll
    for (int r = 0; r < 4; ++r) {
      float re = Zrr[s][r] + Zii[s][r];   // a * conj(b)
      float im = Zir[s][r] - Zri[s][r];
      P[(lrb + r) * 64 + lc] = make_float2(re, im);
    }
  }
}

// ---------------- reduce (combined, 416 blocks) ----------------
__global__ __launch_bounds__(256) void k_reduce(float* __restrict__ ws) {
  int bid = blockIdx.x, tid = threadIdx.x;
  if (bid < 160) {
    const float2* PA = (const float2*)(ws + OFF_PA);
    float2* R2 = (float2*)ws;
    int t = bid >> 4;
    int e = ((bid & 15) << 8) + tid;
    float sx = 0.f, sy = 0.f;
#pragma unroll 4
    for (int k = 0; k < 32; ++k) {
      float2 p = PA[(size_t)(k * 10 + t) * 4096 + e];
      sx += p.x; sy += p.y;
    }
    int ti, tj;
    tile_ij(t, ti, tj);
    int i = ti * 64 + (e >> 6), j = tj * 64 + (e & 63);
    if (i == j) sx += 0.01f;
    R2[i * 256 + j] = make_float2(sx, sy);
  } else {
    const float2* PX = (const float2*)(ws + OFF_PX);
    ushort_t* dst = (ushort_t*)(ws + OFF_GP);
    int idx = (bid - 160) * 256 + tid;
    int i = idx >> 8, j = idx & 255;
    int ii = i, jj = j;
    float sgn = 1.f;
    if ((i >> 6) < (j >> 6)) { ii = j; jj = i; sgn = -1.f; }
    int ti = ii >> 6, tj = jj >> 6;
    int t = ((ti * (ti + 1)) >> 1) + tj;
    int e = ((ii & 63) << 6) + (jj & 63);
    float sx = 0.f, sy = 0.f;
#pragma unroll 4
    for (int k = 0; k < 16; ++k) {
      float2 p = PX[(size_t)(k * 10 + t) * 4096 + e];
      sx += p.x; sy += p.y;
    }
    sy *= sgn;
    ushort_t h, l;
    split_bf16(sx, h, l);
    dst[idx] = h;
    dst[idx + 65536] = l;
    split_bf16(sy, h, l);
    dst[idx + 131072] = h;
    dst[idx + 196608] = l;
  }
}

// ---------------- n1p: elementwise E0 (rm+tr) and X1 (tr) planes from R ----------------
__global__ __launch_bounds__(256) void k_n1p(float* __restrict__ ws) {
  const float2* R = (const float2*)ws;
  ushort_t* e0 = (ushort_t*)(ws + OFF_E0P);
  ushort_t* e0t = e0 + 262144;
  ushort_t* x1t = (ushort_t*)(ws + OFF_XAT);
  int idx = blockIdx.x * 256 + threadIdx.x;
  int i = idx >> 8, j = idx & 255;
  float Dii = R[i * 257].x, Djj = R[j * 257].x;
  float2 r = r_mirror(R, i, j);
  float dl = (i == j) ? 1.0f : 0.0f;
  float ex = dl - r.x / Dii, ey = -r.y / Dii;
  float xx = (dl + ex) / Djj, xy = ey / Djj;
  int rm = i * 256 + j, trn = j * 256 + i;
  ushort_t h, l;
  split_bf16(ex, h, l);
  e0[rm] = h; e0[rm + 65536] = l;
  e0t[trn] = h; e0t[trn + 65536] = l;
  split_bf16(ey, h, l);
  e0[rm + 131072] = h; e0[rm + 196608] = l;
  e0t[trn + 131072] = h; e0t[trn + 196608] = l;
  split_bf16(xx, h, l);
  x1t[trn] = h; x1t[trn + 65536] = l;
  split_bf16(xy, h, l);
  x1t[trn + 131072] = h; x1t[trn + 196608] = l;
}

// ---------------- prim: 256^3 complex MFMA product, 64-row x 16-col tiles --------------
__global__ __launch_bounds__(256) void k_prim(const ushort_t* __restrict__ Arm,
                                              const ushort_t* __restrict__ BtrE,
                                              const ushort_t* __restrict__ BtrX,
                                              const ushort_t* __restrict__ AddX,
                                              ushort_t* __restrict__ EoutRm,
                                              ushort_t* __restrict__ EoutTr,
                                              ushort_t* __restrict__ XoutTr,
                                              ushort_t* __restrict__ XoutRm,
                                              int nEjobs) {
  __shared__ __align__(16) ushort_t sB[4][16][40];
  int job = blockIdx.x;
  bool isE = job < nEjobs;
  int b = isE ? job : job - nEjobs;
  const ushort_t* Bp = isE ? BtrE : BtrX;
  const ushort_t* Add = isE ? (const ushort_t*)nullptr : AddX;
  ushort_t* Otr = isE ? EoutTr : XoutTr;
  ushort_t* Orm = isE ? EoutRm : XoutRm;
  int j0 = (b & 15) * 16, i0 = (b >> 4) * 64;
  int tid = threadIdx.x;
  int lane = tid & 63, wv = tid >> 6;
  int sp = tid >> 6;
  int srow = (tid >> 2) & 15, sslot = tid & 3;
  int m = i0 + wv * 16 + (lane & 15);
  int kq = (lane >> 4) * 8;
  f32x4 Zrr = {0.f, 0.f, 0.f, 0.f}, Zri = Zrr, Zir = Zrr, Zii = Zrr;
  for (int k0 = 0; k0 < 256; k0 += 32) {
    __syncthreads();
    *(bf16x8*)&sB[sp][srow][sslot * 8] =
        *(const bf16x8*)(Bp + (size_t)sp * 65536 + (size_t)(j0 + srow) * 256 + k0 + sslot * 8);
    __syncthreads();
    size_t ao = (size_t)m * 256 + k0 + kq;
    bf16x8 arh = *(const bf16x8*)(Arm + ao);
    bf16x8 arl = *(const bf16x8*)(Arm + 65536 + ao);
    bf16x8 aih = *(const bf16x8*)(Arm + 131072 + ao);
    bf16x8 ail = *(const bf16x8*)(Arm + 196608 + ao);
    int brow = lane & 15;
    bf16x8 brh = *(const bf16x8*)&sB[0][brow][kq];
    bf16x8 brl = *(const bf16x8*)&sB[1][brow][kq];
    bf16x8 bih = *(const bf16x8*)&sB[2][brow][kq];
    bf16x8 bil = *(const bf16x8*)&sB[3][brow][kq];
    MFMA3(Zrr, arh, arl, brh, brl);
    MFMA3(Zri, arh, arl, bih, bil);
    MFMA3(Zir, aih, ail, brh, brl);
    MFMA3(Zii, aih, ail, bih, bil);
  }
  int rbase = i0 + wv * 16 + (lane >> 4) * 4;
  int col = j0 + (lane & 15);
  size_t wo = (size_t)col * 256 + rbase;
  us4 adr, adl, adi, adj;
  if (Add) {
    adr = *(const us4*)(Add + wo);
    adl = *(const us4*)(Add + 65536 + wo);
    adi = *(const us4*)(Add + 131072 + wo);
    adj = *(const us4*)(Add + 196608 + wo);
  }
  us4 hr, lr, hi, li;
#pragma unroll
  for (int r = 0; r < 4; ++r) {
    float re = Zrr[r] - Zii[r];   // complex a*b
    float im = Zri[r] + Zir[r];
    if (Add) {
      re += bfu2f(adr[r]) + bfu2f(adl[r]);
      im += bfu2f(adi[r]) + bfu2f(adj[r]);
    }
    ushort_t h, l;
    split_bf16(re, h, l); hr[r] = h; lr[r] = l;
    split_bf16(im, h, l); hi[r] = h; li[r] = l;
  }
  if (Otr) {
    *(us4*)(Otr + wo) = hr;
    *(us4*)(Otr + 65536 + wo) = lr;
    *(us4*)(Otr + 131072 + wo) = hi;
    *(us4*)(Otr + 196608 + wo) = li;
  }
  if (Orm) {
#pragma unroll
    for (int r = 0; r < 4; ++r) {
      size_t o = (size_t)(rbase + r) * 256 + col;
      Orm[o] = hr[r];
      Orm[o + 65536] = lr[r];
      Orm[o + 131072] = hi[r];
      Orm[o + 196608] = li[r];
    }
  }
}

// ---------------- wide MFMA ----------------
__global__ __launch_bounds__(256) void k_wide_mfma(const ushort_t* __restrict__ Ap,
                                                   const ushort_t* __restrict__ Bp,
                                                   const float* __restrict__ AuxRe,
                                                   const float* __restrict__ AuxIm,
                                                   ushort_t* __restrict__ WTout,
                                                   float* __restrict__ dq, int mode) {
  __shared__ __align__(16) ushort_t sB[4][32][40];
  const ushort_t* arh_p = Ap;
  const ushort_t* arl_p = Ap + 65536;
  const ushort_t* aih_p = Ap + 131072;
  const ushort_t* ail_p = Ap + 196608;
  const ushort_t* brh_p = Bp;
  const ushort_t* brl_p = Bp + 1048576;
  const ushort_t* bih_p = Bp + 2097152;
  const ushort_t* bil_p = Bp + 3145728;
  int job = blockIdx.x;
  int j0 = (job & 127) * 32;
  int i0 = (job >> 7) * 64;
  int tid = threadIdx.x;
  int lane = tid & 63, wv = tid >> 6;
  int spos = tid & 127;
  int srow = spos >> 2, sslot = spos & 3;
  int p0 = (tid >> 7) * 2;
  const ushort_t* bp0 = (p0 == 0) ? brh_p : bih_p;
  const ushort_t* bp1 = (p0 == 0) ? brl_p : bil_p;
  int m = i0 + wv * 16 + (lane & 15);
  int kq = (lane >> 4) * 8;
  f32x4 z = {0.f, 0.f, 0.f, 0.f};
  f32x4 Zrr[2], Zri[2], Zir[2], Zii[2];
#pragma unroll
  for (int s = 0; s < 2; ++s) { Zrr[s] = z; Zri[s] = z; Zir[s] = z; Zii[s] = z; }
  for (int k0 = 0; k0 < 256; k0 += 32) {
    __syncthreads();
    {
      size_t bo = (size_t)(j0 + srow) * 256 + k0 + sslot * 8;
      *(bf16x8*)&sB[p0][srow][sslot * 8] = *(const bf16x8*)(bp0 + bo);
      *(bf16x8*)&sB[p0 + 1][srow][sslot * 8] = *(const bf16x8*)(bp1 + bo);
    }
    __syncthreads();
    size_t ao = (size_t)m * 256 + k0 + kq;
    bf16x8 arh = *(const bf16x8*)(arh_p + ao);
    bf16x8 arl = *(const bf16x8*)(arl_p + ao);
    bf16x8 aih = *(const bf16x8*)(aih_p + ao);
    bf16x8 ail = *(const bf16x8*)(ail_p + ao);
#pragma unroll
    for (int s = 0; s < 2; ++s) {
      int brow = s * 16 + (lane & 15);
      bf16x8 brh = *(const bf16x8*)&sB[0][brow][kq];
      bf16x8 brl = *(const bf16x8*)&sB[1][brow][kq];
      bf16x8 bih = *(const bf16x8*)&sB[2][brow][kq];
      bf16x8 bil = *(const bf16x8*)&sB[3][brow][kq];
      MFMA3(Zrr[s], arh, arl, brh, brl);
      MFMA3(Zri[s], arh, arl, bih, bil);
      MFMA3(Zir[s], aih, ail, brh, brl);
      MFMA3(Zii[s], aih, ail, bih, bil);
    }
  }
  int rbase = i0 + wv * 16 + (lane >> 4) * 4;
#pragma unroll
  for (int s = 0; s < 2; ++s) {
    int col = j0 + s * 16 + (lane & 15);
    size_t wo = (size_t)col * 256 + rbase;
    float part = 0.f;
    if (mode == 0) {
      us4 hr, lr, hi, li;
#pragma unroll
      for (int r = 0; r < 4; ++r) {
        float re = Zrr[s][r] - Zii[s][r];
        float im = Zri[s][r] + Zir[s][r];
        ushort_t h, l;
        split_bf16(re, h, l);
        hr[r] = h; lr[r] = l;
        split_bf16(im, h, l);
        hi[r] = h; li[r] = l;
        size_t o = (size_t)(rbase + r) * LL + col;
        part += re * AuxRe[o] - im * AuxIm[o];
      }
      *(us4*)(WTout + wo) = hr;
      *(us4*)(WTout + 1048576 + wo) = lr;
      *(us4*)(WTout + 2097152 + wo) = hi;
      *(us4*)(WTout + 3145728 + wo) = li;
    } else {
      us4 wh = *(const us4*)(brh_p + wo);
      us4 wl = *(const us4*)(brl_p + wo);
      us4 wih = *(const us4*)(bih_p + wo);
      us4 wil = *(const us4*)(bil_p + wo);
#pragma unroll
      for (int r = 0; r < 4; ++r) {
        float re = Zrr[s][r] - Zii[s][r];
        float im = Zri[s][r] + Zir[s][r];
        float wx = bfu2f(wh[r]) + bfu2f(wl[r]);
        float wy = bfu2f(wih[r]) + bfu2f(wil[r]);
        part += wx * re + wy * im;
      }
    }
    part += __shfl_down(part, 32);
    part += __shfl_down(part, 16);
    if ((lane >> 4) == 0) atomicAdd(dq + col, part);
  }
}

// ---------------- v,u + LayerNorm (1024 threads, single pass) ----------------
__global__ __launch_bounds__(1024) void k_uvln(float* __restrict__ ws,
                                               const float* __restrict__ gamma,
                                               const float* __restrict__ delta,
                                               const float* __restrict__ lnw,
                                               const float* __restrict__ lnb) {
  __shared__ float sh[16];
  int tid = threadIdx.x, lane = tid & 63, wv = tid >> 6;
  float4 q4 = ((const float4*)(ws + OFF_Q))[tid];
  float4 d4 = ((const float4*)(ws + OFF_D))[tid];
  float4 g4 = ((const float4*)gamma)[tid];
  float dlt = 1.0f / (1.0f + expf(-delta[0]));
  float v0 = q4.x / (d4.x + 1e-12f), v1 = q4.y / (d4.y + 1e-12f);
  float v2 = q4.z / (d4.z + 1e-12f), v3 = q4.w / (d4.w + 1e-12f);
  float u0 = g4.x + dlt * (v0 - g4.x), u1 = g4.y + dlt * (v1 - g4.y);
  float u2 = g4.z + dlt * (v2 - g4.z), u3 = g4.w + dlt * (v3 - g4.w);
  ((float4*)(ws + OFF_V))[tid] = make_float4(v0, v1, v2, v3);
  ((float4*)(ws + OFF_U))[tid] = make_float4(u0, u1, u2, u3);
  float s = wave_red_sum(u0 + u1 + u2 + u3);
  if (lane == 0) sh[wv] = s;
  __syncthreads();
  float mu = 0.f;
#pragma unroll
  for (int w = 0; w < 16; ++w) mu += sh[w];
  mu *= (1.0f / LL);
  __syncthreads();
  float d0 = u0 - mu, d1 = u1 - mu, d2 = u2 - mu, d3 = u3 - mu;
  float s2 = wave_red_sum(d0 * d0 + d1 * d1 + d2 * d2 + d3 * d3);
  if (lane == 0) sh[wv] = s2;
  __syncthreads();
  float var = 0.f;
#pragma unroll
  for (int w = 0; w < 16; ++w) var += sh[w];
  var *= (1.0f / LL);
  float inv = rsqrtf(var + 1e-5f);
  float4 w4 = ((const float4*)lnw)[tid];
  float4 b4 = ((const float4*)lnb)[tid];
  ((float4*)(ws + OFF_UP))[tid] =
      make_float4(d0 * inv * w4.x + b4.x, d1 * inv * w4.y + b4.y,
                  d2 * inv * w4.z + b4.z, d3 * inv * w4.w + b4.w);
}

// ---------------- gate + attention + combine ----------------
__global__ __launch_bounds__(256) void k_gateattn(const float* __restrict__ ws,
                                                  const float* __restrict__ Wg,
                                                  const float* __restrict__ gb,
                                                  const float* __restrict__ inw,
                                                  const float* __restrict__ inb,
                                                  const float* __restrict__ outw,
                                                  const float* __restrict__ outb,
                                                  const float* __restrict__ gamma,
                                                  const float* __restrict__ lmbda,
                                                  float* __restrict__ out) {
  const float* uvec = ws + OFF_U;
  const float* up = ws + OFF_UP;
  const float* vvec = ws + OFF_V;
  int i = blockIdx.x, tid = threadIdx.x;
  const float4* wr = (const float4*)(Wg + (size_t)i * LL);
  const float4* u4 = (const float4*)uvec;
  float s = 0.f;
  for (int j = tid; j < LL / 4; j += 256) {
    float4 w = wr[j], x = u4[j];
    s += w.x * x.x + w.y * x.y + w.z * x.z + w.w * x.w;
  }
  float tot = blk_red_sum(s);
  float g = 1.0f / (1.0f + expf(-(tot + gb[i])));
  float qv = up[i] * inw[0] + inb[0];
  float w1 = inw[1], b1 = inb[1], w2 = inw[2], b2 = inb[2];
  const float4* up4 = (const float4*)up;
  float mx = -3.4e38f;
  for (int j = tid; j < LL / 4; j += 256) {
    float4 u = up4[j];
    mx = fmaxf(mx, fmaxf(fmaxf(qv * (u.x * w1 + b1), qv * (u.y * w1 + b1)),
                         fmaxf(qv * (u.z * w1 + b1), qv * (u.w * w1 + b1))));
  }
  mx = blk_red_max(mx);
  float den = 0.f, num = 0.f;
  for (int j = tid; j < LL / 4; j += 256) {
    float4 u = up4[j];
    float e0 = expf(qv * (u.x * w1 + b1) - mx);
    float e1 = expf(qv * (u.y * w1 + b1) - mx);
    float e2 = expf(qv * (u.z * w1 + b1) - mx);
    float e3 = expf(qv * (u.w * w1 + b1) - mx);
    den += e0 + e1 + e2 + e3;
    num += e0 * (u.x * w2 + b2) + e1 * (u.y * w2 + b2) + e2 * (u.z * w2 + b2) + e3 * (u.w * w2 + b2);
  }
  den = blk_red_sum(den);
  num = blk_red_sum(num);
  if (tid == 0) {
    float attn = (num / den) * outw[0] + outb[0];
    float r = g * vvec[i] + (1.0f - g) * gamma[i] + attn - lmbda[0];
    out[i] = fmaxf(r, 0.0f);
  }
}

extern "C" void kernel_launch(void* const* d_in, const int* in_sizes, int n_in,
                              void* d_out, int out_size, void* d_ws, size_t ws_size,
                              hipStream_t stream) {
  const float* gamma = (const float*)d_in[0];
  const float* Are   = (const float*)d_in[1];
  const float* Aim   = (const float*)d_in[2];
  const float* Xre   = (const float*)d_in[3];
  const float* Xim   = (const float*)d_in[4];
  const float* lnw   = (const float*)d_in[5];
  const float* lnb   = (const float*)d_in[6];
  const float* inw   = (const float*)d_in[7];
  const float* inb   = (const float*)d_in[8];
  const float* outw  = (const float*)d_in[9];
  const float* outb  = (const float*)d_in[10];
  const float* gateW = (const float*)d_in[11];
  const float* gateb = (const float*)d_in[12];
  const float* delta = (const float*)d_in[13];
  const float* lmbda = (const float*)d_in[14];
  float* out = (float*)d_out;
  float* ws = (float*)d_ws;

  ushort_t* e0rm = (ushort_t*)(ws + OFF_E0P);
  ushort_t* e0tr = e0rm + 262144;
  ushort_t* eArm = (ushort_t*)(ws + OFF_EAP);
  ushort_t* eAtr = eArm + 262144;
  ushort_t* eBrm = (ushort_t*)(ws + OFF_EBP);
  ushort_t* eBtr = eBrm + 262144;
  ushort_t* xAt = (ushort_t*)(ws + OFF_XAT);
  ushort_t* xBt = (ushort_t*)(ws + OFF_XBT);
  ushort_t* Rinvp = (ushort_t*)(ws + OFF_RINVP);

  k_prep<<<2568, 256, 0, stream>>>(ws, Are, Aim, Xre, Xim, gamma);
  k_gram_both<<<480, 256, 0, stream>>>(ws);
  k_reduce<<<416, 256, 0, stream>>>(ws);
  // Newton chain on split-bf16 planes (MFMA), 16-col tiles:
  k_n1p<<<256, 256, 0, stream>>>(ws);                                  // E0 rm+tr, X1 tr
  k_prim<<<64, 256, 0, stream>>>(e0rm, e0tr, nullptr, nullptr,
                                 eArm, eAtr, nullptr, nullptr, 64);    // E1 = E0^2
  k_prim<<<128, 256, 0, stream>>>(eArm, eAtr, xAt, xAt,
                                  eBrm, eBtr, xBt, nullptr, 64);       // E2, X2
  k_prim<<<128, 256, 0, stream>>>(eBrm, eBtr, xBt, xBt,
                                  eArm, eAtr, xAt, nullptr, 64);       // E3, X3
  k_prim<<<128, 256, 0, stream>>>(eArm, eAtr, xAt, xAt,
                                  eBrm, eBtr, xBt, nullptr, 64);       // E4, X4
  k_prim<<<64, 256, 0, stream>>>(eBrm, nullptr, xBt, xBt,
                                 nullptr, nullptr, nullptr, Rinvp, 0); // X5 -> Rinvp
  k_wide_mfma<<<512, 256, 0, stream>>>(Rinvp, (const ushort_t*)(ws + OFF_ATP),
                                       Are, Aim, (ushort_t*)(ws + OFF_WTP),
                                       ws + OFF_D, 0);
  k_wide_mfma<<<512, 256, 0, stream>>>((const ushort_t*)(ws + OFF_GP),
                                       (const ushort_t*)(ws + OFF_WTP),
                                       nullptr, nullptr, nullptr, ws + OFF_Q, 1);
  k_uvln<<<1, 1024, 0, stream>>>(ws, gamma, delta, lnw, lnb);
  k_gateattn<<<LL, 256, 0, stream>>>(ws, gateW, gateb, inw, inb, outw, outb,
                                     gamma, lmbda, out);
}